// Round 1
// baseline (71.956 us; speedup 1.0000x reference)
//
#include <hip/hip_runtime.h>
#include <hip/hip_bf16.h>

#define SS   2048
#define DD   128
#define QBLK 64
#define KBLK 64

typedef __attribute__((ext_vector_type(8))) short short8;   // 8 bf16 = 4 VGPRs (MFMA A/B frag)
typedef __attribute__((ext_vector_type(4))) float f32x4;    // MFMA C/D frag

__device__ __forceinline__ unsigned short f2bf(float x) {
  // RNE f32 -> bf16 via native cast (compiler emits HW cvt on gfx950)
  return __builtin_bit_cast(unsigned short, (__bf16)x);
}

// sigma: Vt column permutation so PV B-frag (slot j = key [g0 i0..3, g1 i0..3]) is contiguous.
// pos = (a&32) | ((a>>2 & 3)<<3) | ((a>>4 & 1)<<2) | (a&3)
__device__ __forceinline__ int sigma_col(int a) {
  return (a & 35) | ((a & 12) << 1) | ((a & 16) >> 2);
}

__global__ __launch_bounds__(256) void sdpa_causal_kernel(
    const float* __restrict__ Q, const float* __restrict__ K,
    const float* __restrict__ V, float* __restrict__ O)
{
  __shared__ __align__(16) char smem[KBLK * DD * 2 + DD * KBLK * 2];  // 16KB K + 16KB Vt
  char* Klds  = smem;
  char* Vtlds = smem + KBLK * DD * 2;

  const int b   = blockIdx.x;                    // batch -> XCD pin (linear%8 == b%8)
  const int qb  = (int)gridDim.y - 1 - (int)blockIdx.y;  // heavy (long) blocks dispatch first
  const int q0  = qb * QBLK;
  const int tid = threadIdx.x;
  const int lane = tid & 63;
  const int wid  = tid >> 6;
  const int l15  = lane & 15;
  const int hi   = lane >> 4;

  const float* Qb = Q + (size_t)b * SS * DD;
  const float* Kb = K + (size_t)b * SS * DD;
  const float* Vb = V + (size_t)b * SS * DD;
  float*       Ob = O + (size_t)b * SS * DD;

  const float scale = 0.08838834764831845f;  // 1/sqrt(128)

  // ---- Q fragments (B-operand of swapped QK^T), scale folded in ----
  // lane holds Q[q0 + wid*16 + l15][32c + 8hi + j], j=0..7
  short8 qf[4];
  {
    const float* qrow = Qb + (size_t)(q0 + wid * 16 + l15) * DD;
    #pragma unroll
    for (int c = 0; c < 4; ++c) {
      const float4* p = reinterpret_cast<const float4*>(qrow + 32 * c + 8 * hi);
      float4 x = p[0], y = p[1];
      short8 w;
      w[0] = f2bf(x.x * scale); w[1] = f2bf(x.y * scale);
      w[2] = f2bf(x.z * scale); w[3] = f2bf(x.w * scale);
      w[4] = f2bf(y.x * scale); w[5] = f2bf(y.y * scale);
      w[6] = f2bf(y.z * scale); w[7] = f2bf(y.w * scale);
      qf[c] = w;
    }
  }

  f32x4 o[8];
  #pragma unroll
  for (int nt = 0; nt < 8; ++nt) o[nt] = (f32x4){0.f, 0.f, 0.f, 0.f};
  float m = -INFINITY;
  float lsum = 0.f;

  const int ntile = qb + 1;
  for (int t = 0; t < ntile; ++t) {
    const int kv0 = t * KBLK;
    if (t) __syncthreads();

    // ---- stage K tile: row-major bf16 [64][128], swizzle byte ^= (row&7)<<4 ----
    #pragma unroll
    for (int u = 0; u < 4; ++u) {
      int row = u * 16 + (tid >> 4);
      int col = 8 * (tid & 15);
      const float4* sp = reinterpret_cast<const float4*>(Kb + (size_t)(kv0 + row) * DD + col);
      float4 x = sp[0], y = sp[1];
      short8 w;
      w[0] = f2bf(x.x); w[1] = f2bf(x.y); w[2] = f2bf(x.z); w[3] = f2bf(x.w);
      w[4] = f2bf(y.x); w[5] = f2bf(y.y); w[6] = f2bf(y.z); w[7] = f2bf(y.w);
      int byteoff = row * 256 + col * 2;
      byteoff ^= (row & 7) << 4;
      *reinterpret_cast<short8*>(Klds + byteoff) = w;
    }
    // ---- stage V transposed: Vt[d][sigma(key)] bf16, swizzle ((d>>3)^d)&7 <<4 ----
    #pragma unroll
    for (int u = 0; u < 4; ++u) {
      int row = u * 16 + (tid >> 4);       // key
      int col = 8 * (tid & 15);            // d base
      const float4* sp = reinterpret_cast<const float4*>(Vb + (size_t)(kv0 + row) * DD + col);
      float4 x = sp[0], y = sp[1];
      int sc = sigma_col(row);
      float vals[8] = {x.x, x.y, x.z, x.w, y.x, y.y, y.z, y.w};
      #pragma unroll
      for (int j = 0; j < 8; ++j) {
        int d = col + j;
        int byteoff = (d << 7) + (sc << 1);
        byteoff ^= (((d >> 3) ^ d) & 7) << 4;
        *reinterpret_cast<unsigned short*>(Vtlds + byteoff) = f2bf(vals[j]);
      }
    }
    __syncthreads();

    // ---- swapped QK^T: S^T = K · Q^T  (lane: row=key 4hi+i, col=q l15) ----
    f32x4 sacc[4];
    #pragma unroll
    for (int g = 0; g < 4; ++g) {
      f32x4 acc = {0.f, 0.f, 0.f, 0.f};
      #pragma unroll
      for (int c = 0; c < 4; ++c) {
        int row = g * 16 + l15;
        int byteoff = row * 256 + (32 * c + 8 * hi) * 2;
        byteoff ^= (row & 7) << 4;
        short8 kf = *reinterpret_cast<const short8*>(Klds + byteoff);
        acc = __builtin_amdgcn_mfma_f32_16x16x32_bf16(kf, qf[c], acc, 0, 0, 0);
      }
      sacc[g] = acc;
    }

    // ---- causal mask (diagonal tile only) ----
    if (t == ntile - 1) {
      const int q = q0 + wid * 16 + l15;
      #pragma unroll
      for (int g = 0; g < 4; ++g)
        #pragma unroll
        for (int i = 0; i < 4; ++i) {
          int key = kv0 + g * 16 + 4 * hi + i;
          if (key > q) sacc[g][i] = -1e30f;
        }
    }

    // ---- online softmax (row = q = l15; reduce over own 16 + shfl hi groups) ----
    float tmax = -INFINITY;
    #pragma unroll
    for (int g = 0; g < 4; ++g)
      #pragma unroll
      for (int i = 0; i < 4; ++i) tmax = fmaxf(tmax, sacc[g][i]);
    tmax = fmaxf(tmax, __shfl_xor(tmax, 16));
    tmax = fmaxf(tmax, __shfl_xor(tmax, 32));
    float mnew = fmaxf(m, tmax);
    float corr = __expf(m - mnew);   // m=-inf first tile -> 0
    m = mnew;

    float p[4][4];
    float psum = 0.f;
    #pragma unroll
    for (int g = 0; g < 4; ++g)
      #pragma unroll
      for (int i = 0; i < 4; ++i) {
        float pv = __expf(sacc[g][i] - mnew);
        p[g][i] = pv;
        psum += pv;
      }
    psum += __shfl_xor(psum, 16);
    psum += __shfl_xor(psum, 32);
    lsum = lsum * corr + psum;

    // O rows are q = 4hi+i -> fetch that q's corr from lane 4hi+i
    float corrO[4];
    #pragma unroll
    for (int i = 0; i < 4; ++i) corrO[i] = __shfl(corr, 4 * hi + i);
    #pragma unroll
    for (int nt = 0; nt < 8; ++nt)
      #pragma unroll
      for (int i = 0; i < 4; ++i) o[nt][i] *= corrO[i];

    // ---- P fragments: slot order [g_even i0..3 | g_odd i0..3] matches sigma ----
    short8 pf[2];
    #pragma unroll
    for (int ks = 0; ks < 2; ++ks) {
      short8 w;
      #pragma unroll
      for (int i = 0; i < 4; ++i) {
        w[i]     = f2bf(p[2 * ks][i]);
        w[4 + i] = f2bf(p[2 * ks + 1][i]);
      }
      pf[ks] = w;
    }

    // ---- PV: O[q=4hi+i][d=nt*16+l15] += P · V ----
    #pragma unroll
    for (int ks = 0; ks < 2; ++ks) {
      #pragma unroll
      for (int nt = 0; nt < 8; ++nt) {
        int d = nt * 16 + l15;
        int byteoff = (d << 7) + (ks * 32 + 8 * hi) * 2;
        byteoff ^= (((d >> 3) ^ d) & 7) << 4;
        short8 vf = *reinterpret_cast<const short8*>(Vtlds + byteoff);
        o[nt] = __builtin_amdgcn_mfma_f32_16x16x32_bf16(pf[ks], vf, o[nt], 0, 0, 0);
      }
    }
  }

  // ---- epilogue: normalize and store fp32 ----
  float rl = 1.0f / lsum;
  float rlO[4];
  #pragma unroll
  for (int i = 0; i < 4; ++i) rlO[i] = __shfl(rl, 4 * hi + i);
  const int qrow = q0 + wid * 16;
  #pragma unroll
  for (int nt = 0; nt < 8; ++nt)
    #pragma unroll
    for (int i = 0; i < 4; ++i)
      Ob[(size_t)(qrow + 4 * hi + i) * DD + nt * 16 + l15] = o[nt][i] * rlO[i];
}

extern "C" void kernel_launch(void* const* d_in, const int* in_sizes, int n_in,
                              void* d_out, int out_size, void* d_ws, size_t ws_size,
                              hipStream_t stream) {
  const float* Q = (const float*)d_in[0];
  const float* K = (const float*)d_in[1];
  const float* V = (const float*)d_in[2];
  // d_in[3] = additive causal mask; computed inline instead.
  float* O = (float*)d_out;

  dim3 grid(16, SS / QBLK);   // x = batch (XCD pin), y = q-block (reversed inside)
  dim3 block(256);
  sdpa_causal_kernel<<<grid, block, 0, stream>>>(Q, K, V, O);
}

// Round 2
// 64.813 us; speedup vs baseline: 1.1102x; 1.1102x over previous
//
#include <hip/hip_runtime.h>
#include <hip/hip_bf16.h>
#include <cstdint>

#define SS   2048
#define DD   128
#define QBLK 64
#define KBLK 64
#define NTILES (SS / KBLK)          // 32
#define TILE_BYTES 16384            // 64x128 bf16
#define WS_NEED ((size_t)16 * NTILES * TILE_BYTES * 2)

typedef __attribute__((ext_vector_type(8))) short short8;   // 8 bf16
typedef __attribute__((ext_vector_type(4))) float f32x4;    // MFMA C/D frag

__device__ __forceinline__ unsigned short f2bf(float x) {
  return __builtin_bit_cast(unsigned short, (__bf16)x);
}

// sigma: Vt column permutation so PV B-frag slots are contiguous 16B.
// pos bits = [a0, a1, a4, a2, a3, a5]
__device__ __forceinline__ int sigma_col(int a) {
  return (a & 35) | ((a & 12) << 1) | ((a & 16) >> 2);
}

// ---------------------------------------------------------------------------
// Pre-pass: K -> bf16 swizzled tiles; V -> transposed sigma-permuted swizzled
// tiles. Layout in ws: K tiles [b][t][16KB], then V tiles [b][t][16KB].
// ---------------------------------------------------------------------------
__global__ __launch_bounds__(256) void prepack_kv(
    const float* __restrict__ K, const float* __restrict__ V, char* __restrict__ ws)
{
  __shared__ float vf[64][129];  // padded V tile (f32)
  const int b = blockIdx.x, t = blockIdx.y;
  const int tid = threadIdx.x;
  const float* Kt = K + ((size_t)b * SS + t * KBLK) * DD;
  const float* Vt = V + ((size_t)b * SS + t * KBLK) * DD;
  char* Kd = ws + ((size_t)(b * NTILES + t)) * TILE_BYTES;
  char* Vd = ws + (size_t)16 * NTILES * TILE_BYTES + ((size_t)(b * NTILES + t)) * TILE_BYTES;

  // K: row-major bf16 [64][128], byteoff ^= (row&7)<<4
  #pragma unroll
  for (int u = 0; u < 4; ++u) {
    int row = u * 16 + (tid >> 4);
    int col = 8 * (tid & 15);
    const float4* sp = reinterpret_cast<const float4*>(Kt + (size_t)row * DD + col);
    float4 x = sp[0], y = sp[1];
    short8 w;
    w[0] = f2bf(x.x); w[1] = f2bf(x.y); w[2] = f2bf(x.z); w[3] = f2bf(x.w);
    w[4] = f2bf(y.x); w[5] = f2bf(y.y); w[6] = f2bf(y.z); w[7] = f2bf(y.w);
    int off = (row * 256 + col * 2) ^ ((row & 7) << 4);
    *reinterpret_cast<short8*>(Kd + off) = w;
  }
  // V: stage f32 tile to LDS
  #pragma unroll
  for (int u = 0; u < 4; ++u) {
    int row = u * 16 + (tid >> 4);
    int col = 8 * (tid & 15);
    const float4* sp = reinterpret_cast<const float4*>(Vt + (size_t)row * DD + col);
    float4 x = sp[0], y = sp[1];
    vf[row][col + 0] = x.x; vf[row][col + 1] = x.y; vf[row][col + 2] = x.z; vf[row][col + 3] = x.w;
    vf[row][col + 4] = y.x; vf[row][col + 5] = y.y; vf[row][col + 6] = y.z; vf[row][col + 7] = y.w;
  }
  __syncthreads();
  // Vt: [d][sigma(key)] bf16, byteoff ^= ((d>>3)^d)&7 <<4
  #pragma unroll
  for (int q = 0; q < 4; ++q) {
    int idx = q * 256 + tid;      // 1024 chunks of 16B
    int d = idx >> 3, y = idx & 7;
    short8 w;
    #pragma unroll
    for (int j = 0; j < 8; ++j) {
      // key whose sigma position is y*8+j
      int a = (j & 3) | ((y & 3) << 2) | ((j & 4) << 2) | ((y & 4) << 3);
      w[j] = f2bf(vf[a][d]);
    }
    int off = ((d << 7) + (y << 4)) ^ ((((d >> 3) ^ d) & 7) << 4);
    *reinterpret_cast<short8*>(Vd + off) = w;
  }
}

// ---------------------------------------------------------------------------
// Main kernel: double-buffered LDS, global_load_lds staging, 2-phase pipeline
// ---------------------------------------------------------------------------
__device__ __forceinline__ void stage_tile(const char* Ksrc, const char* Vsrc,
                                           char* Kl, char* Vl, int wid, int lane)
{
  #pragma unroll
  for (int i = 0; i < 4; ++i) {
    int off = wid * 4096 + i * 1024;
    __builtin_amdgcn_global_load_lds(
        (const __attribute__((address_space(1))) unsigned int*)(Ksrc + off + lane * 16),
        (__attribute__((address_space(3))) unsigned int*)(Kl + off), 16, 0, 0);
  }
  #pragma unroll
  for (int i = 0; i < 4; ++i) {
    int off = wid * 4096 + i * 1024;
    __builtin_amdgcn_global_load_lds(
        (const __attribute__((address_space(1))) unsigned int*)(Vsrc + off + lane * 16),
        (__attribute__((address_space(3))) unsigned int*)(Vl + off), 16, 0, 0);
  }
}

__global__ __launch_bounds__(256) void sdpa_causal_v2(
    const float* __restrict__ Q, const char* __restrict__ ws, float* __restrict__ O)
{
  __shared__ __align__(16) char smem[2 * 32768];  // [buf][K 16KB | Vt 16KB]

  const int b = blockIdx.x;
  const int y = blockIdx.y;
  const int qb = (y < 16) ? (31 - y) : (y - 16);  // balanced pairing: slot1+slot2 = 33 tiles
  const int q0 = qb * QBLK;
  const int tid = threadIdx.x;
  const int lane = tid & 63;
  const int wid  = tid >> 6;
  const int l15  = lane & 15;
  const int hi   = lane >> 4;

  const float* Qb = Q + (size_t)b * SS * DD;
  float*       Ob = O + (size_t)b * SS * DD;
  const char*  Kws = ws + ((size_t)b * NTILES) * TILE_BYTES;
  const char*  Vws = ws + (size_t)16 * NTILES * TILE_BYTES + ((size_t)b * NTILES) * TILE_BYTES;

  const float scale = 0.08838834764831845f;  // 1/sqrt(128)

  // Q fragments (B-operand of swapped QK^T), scale folded in
  short8 qf[4];
  {
    const float* qrow = Qb + (size_t)(q0 + wid * 16 + l15) * DD;
    #pragma unroll
    for (int c = 0; c < 4; ++c) {
      const float4* p = reinterpret_cast<const float4*>(qrow + 32 * c + 8 * hi);
      float4 x = p[0], y2 = p[1];
      short8 w;
      w[0] = f2bf(x.x * scale); w[1] = f2bf(x.y * scale);
      w[2] = f2bf(x.z * scale); w[3] = f2bf(x.w * scale);
      w[4] = f2bf(y2.x * scale); w[5] = f2bf(y2.y * scale);
      w[6] = f2bf(y2.z * scale); w[7] = f2bf(y2.w * scale);
      qf[c] = w;
    }
  }

  f32x4 o[8];
  #pragma unroll
  for (int nt = 0; nt < 8; ++nt) o[nt] = (f32x4){0.f, 0.f, 0.f, 0.f};
  float m = -INFINITY;
  float lsum = 0.f;

  const int ntile = qb + 1;
  int cur = 0;

  // prologue: stage tile 0
  stage_tile(Kws, Vws, smem, smem + 16384, wid, lane);
  __syncthreads();

  for (int t = 0; t < ntile; ++t) {
    // stage next tile into the other buffer (overlaps with compute below)
    if (t + 1 < ntile) {
      char* nb = smem + (cur ^ 1) * 32768;
      stage_tile(Kws + (size_t)(t + 1) * TILE_BYTES, Vws + (size_t)(t + 1) * TILE_BYTES,
                 nb, nb + 16384, wid, lane);
    }

    const char* Kl = smem + cur * 32768;
    const char* Vl = Kl + 16384;
    const int kv0 = t * KBLK;

    // ---- swapped QK^T: S^T = K · Q^T ----
    f32x4 sacc[4];
    __builtin_amdgcn_s_setprio(1);
    #pragma unroll
    for (int g = 0; g < 4; ++g) {
      f32x4 acc = {0.f, 0.f, 0.f, 0.f};
      #pragma unroll
      for (int c = 0; c < 4; ++c) {
        int row = g * 16 + l15;
        int byteoff = (row * 256 + (32 * c + 8 * hi) * 2) ^ ((row & 7) << 4);
        short8 kf = *reinterpret_cast<const short8*>(Kl + byteoff);
        acc = __builtin_amdgcn_mfma_f32_16x16x32_bf16(kf, qf[c], acc, 0, 0, 0);
      }
      sacc[g] = acc;
    }
    __builtin_amdgcn_s_setprio(0);

    // ---- causal mask (diagonal tile only) ----
    if (t == ntile - 1) {
      const int q = q0 + wid * 16 + l15;
      #pragma unroll
      for (int g = 0; g < 4; ++g)
        #pragma unroll
        for (int i = 0; i < 4; ++i) {
          int key = kv0 + g * 16 + 4 * hi + i;
          if (key > q) sacc[g][i] = -1e30f;
        }
    }

    // ---- online softmax (row q = l15) ----
    float tmax = -INFINITY;
    #pragma unroll
    for (int g = 0; g < 4; ++g)
      #pragma unroll
      for (int i = 0; i < 4; ++i) tmax = fmaxf(tmax, sacc[g][i]);
    tmax = fmaxf(tmax, __shfl_xor(tmax, 16));
    tmax = fmaxf(tmax, __shfl_xor(tmax, 32));
    float mnew = fmaxf(m, tmax);
    float corr = __expf(m - mnew);
    m = mnew;

    float p[4][4];
    float psum = 0.f;
    #pragma unroll
    for (int g = 0; g < 4; ++g)
      #pragma unroll
      for (int i = 0; i < 4; ++i) {
        float pv = __expf(sacc[g][i] - mnew);
        p[g][i] = pv;
        psum += pv;
      }
    psum += __shfl_xor(psum, 16);
    psum += __shfl_xor(psum, 32);
    lsum = lsum * corr + psum;

    float corrO[4];
    #pragma unroll
    for (int i = 0; i < 4; ++i) corrO[i] = __shfl(corr, 4 * hi + i);
    #pragma unroll
    for (int nt = 0; nt < 8; ++nt)
      #pragma unroll
      for (int i = 0; i < 4; ++i) o[nt][i] *= corrO[i];

    // ---- P fragments (slot order matches sigma) ----
    short8 pf[2];
    #pragma unroll
    for (int ks = 0; ks < 2; ++ks) {
      short8 w;
      #pragma unroll
      for (int i = 0; i < 4; ++i) {
        w[i]     = f2bf(p[2 * ks][i]);
        w[4 + i] = f2bf(p[2 * ks + 1][i]);
      }
      pf[ks] = w;
    }

    // ---- PV ----
    __builtin_amdgcn_s_setprio(1);
    #pragma unroll
    for (int ks = 0; ks < 2; ++ks) {
      #pragma unroll
      for (int nt = 0; nt < 8; ++nt) {
        int d = nt * 16 + l15;
        int byteoff = ((d << 7) + (ks * 32 + 8 * hi) * 2) ^ ((((d >> 3) ^ d) & 7) << 4);
        short8 vvf = *reinterpret_cast<const short8*>(Vl + byteoff);
        o[nt] = __builtin_amdgcn_mfma_f32_16x16x32_bf16(pf[ks], vvf, o[nt], 0, 0, 0);
      }
    }
    __builtin_amdgcn_s_setprio(0);

    if (t + 1 < ntile) {
      __syncthreads();   // drains vmcnt(0): next tile's loads landed; buf read-protected
      cur ^= 1;
    }
  }

  // ---- epilogue ----
  float rl = 1.0f / lsum;
  float rlO[4];
  #pragma unroll
  for (int i = 0; i < 4; ++i) rlO[i] = __shfl(rl, 4 * hi + i);
  const int qrow = q0 + wid * 16;
  #pragma unroll
  for (int nt = 0; nt < 8; ++nt)
    #pragma unroll
    for (int i = 0; i < 4; ++i)
      Ob[(size_t)(qrow + 4 * hi + i) * DD + nt * 16 + l15] = o[nt][i] * rlO[i];
}

// ---------------------------------------------------------------------------
// Fallback (round-1 kernel) if ws is too small
// ---------------------------------------------------------------------------
__global__ __launch_bounds__(256) void sdpa_causal_kernel(
    const float* __restrict__ Q, const float* __restrict__ K,
    const float* __restrict__ V, float* __restrict__ O)
{
  __shared__ __align__(16) char smem[KBLK * DD * 2 + DD * KBLK * 2];
  char* Klds  = smem;
  char* Vtlds = smem + KBLK * DD * 2;

  const int b   = blockIdx.x;
  const int qb  = (int)gridDim.y - 1 - (int)blockIdx.y;
  const int q0  = qb * QBLK;
  const int tid = threadIdx.x;
  const int lane = tid & 63;
  const int wid  = tid >> 6;
  const int l15  = lane & 15;
  const int hi   = lane >> 4;

  const float* Qb = Q + (size_t)b * SS * DD;
  const float* Kb = K + (size_t)b * SS * DD;
  const float* Vb = V + (size_t)b * SS * DD;
  float*       Ob = O + (size_t)b * SS * DD;

  const float scale = 0.08838834764831845f;

  short8 qf[4];
  {
    const float* qrow = Qb + (size_t)(q0 + wid * 16 + l15) * DD;
    #pragma unroll
    for (int c = 0; c < 4; ++c) {
      const float4* p = reinterpret_cast<const float4*>(qrow + 32 * c + 8 * hi);
      float4 x = p[0], y = p[1];
      short8 w;
      w[0] = f2bf(x.x * scale); w[1] = f2bf(x.y * scale);
      w[2] = f2bf(x.z * scale); w[3] = f2bf(x.w * scale);
      w[4] = f2bf(y.x * scale); w[5] = f2bf(y.y * scale);
      w[6] = f2bf(y.z * scale); w[7] = f2bf(y.w * scale);
      qf[c] = w;
    }
  }

  f32x4 o[8];
  #pragma unroll
  for (int nt = 0; nt < 8; ++nt) o[nt] = (f32x4){0.f, 0.f, 0.f, 0.f};
  float m = -INFINITY;
  float lsum = 0.f;

  const int ntile = qb + 1;
  for (int t = 0; t < ntile; ++t) {
    const int kv0 = t * KBLK;
    if (t) __syncthreads();

    #pragma unroll
    for (int u = 0; u < 4; ++u) {
      int row = u * 16 + (tid >> 4);
      int col = 8 * (tid & 15);
      const float4* sp = reinterpret_cast<const float4*>(Kb + (size_t)(kv0 + row) * DD + col);
      float4 x = sp[0], y = sp[1];
      short8 w;
      w[0] = f2bf(x.x); w[1] = f2bf(x.y); w[2] = f2bf(x.z); w[3] = f2bf(x.w);
      w[4] = f2bf(y.x); w[5] = f2bf(y.y); w[6] = f2bf(y.z); w[7] = f2bf(y.w);
      int byteoff = (row * 256 + col * 2) ^ ((row & 7) << 4);
      *reinterpret_cast<short8*>(Klds + byteoff) = w;
    }
    #pragma unroll
    for (int u = 0; u < 4; ++u) {
      int row = u * 16 + (tid >> 4);
      int col = 8 * (tid & 15);
      const float4* sp = reinterpret_cast<const float4*>(Vb + (size_t)(kv0 + row) * DD + col);
      float4 x = sp[0], y = sp[1];
      int sc = sigma_col(row);
      float vals[8] = {x.x, x.y, x.z, x.w, y.x, y.y, y.z, y.w};
      #pragma unroll
      for (int j = 0; j < 8; ++j) {
        int d = col + j;
        int byteoff = ((d << 7) + (sc << 1)) ^ ((((d >> 3) ^ d) & 7) << 4);
        *reinterpret_cast<unsigned short*>(Vtlds + byteoff) = f2bf(vals[j]);
      }
    }
    __syncthreads();

    f32x4 sacc[4];
    #pragma unroll
    for (int g = 0; g < 4; ++g) {
      f32x4 acc = {0.f, 0.f, 0.f, 0.f};
      #pragma unroll
      for (int c = 0; c < 4; ++c) {
        int row = g * 16 + l15;
        int byteoff = (row * 256 + (32 * c + 8 * hi) * 2) ^ ((row & 7) << 4);
        short8 kf = *reinterpret_cast<const short8*>(Klds + byteoff);
        acc = __builtin_amdgcn_mfma_f32_16x16x32_bf16(kf, qf[c], acc, 0, 0, 0);
      }
      sacc[g] = acc;
    }

    if (t == ntile - 1) {
      const int q = q0 + wid * 16 + l15;
      #pragma unroll
      for (int g = 0; g < 4; ++g)
        #pragma unroll
        for (int i = 0; i < 4; ++i) {
          int key = kv0 + g * 16 + 4 * hi + i;
          if (key > q) sacc[g][i] = -1e30f;
        }
    }

    float tmax = -INFINITY;
    #pragma unroll
    for (int g = 0; g < 4; ++g)
      #pragma unroll
      for (int i = 0; i < 4; ++i) tmax = fmaxf(tmax, sacc[g][i]);
    tmax = fmaxf(tmax, __shfl_xor(tmax, 16));
    tmax = fmaxf(tmax, __shfl_xor(tmax, 32));
    float mnew = fmaxf(m, tmax);
    float corr = __expf(m - mnew);
    m = mnew;

    float p[4][4];
    float psum = 0.f;
    #pragma unroll
    for (int g = 0; g < 4; ++g)
      #pragma unroll
      for (int i = 0; i < 4; ++i) {
        float pv = __expf(sacc[g][i] - mnew);
        p[g][i] = pv;
        psum += pv;
      }
    psum += __shfl_xor(psum, 16);
    psum += __shfl_xor(psum, 32);
    lsum = lsum * corr + psum;

    float corrO[4];
    #pragma unroll
    for (int i = 0; i < 4; ++i) corrO[i] = __shfl(corr, 4 * hi + i);
    #pragma unroll
    for (int nt = 0; nt < 8; ++nt)
      #pragma unroll
      for (int i = 0; i < 4; ++i) o[nt][i] *= corrO[i];

    short8 pf[2];
    #pragma unroll
    for (int ks = 0; ks < 2; ++ks) {
      short8 w;
      #pragma unroll
      for (int i = 0; i < 4; ++i) {
        w[i]     = f2bf(p[2 * ks][i]);
        w[4 + i] = f2bf(p[2 * ks + 1][i]);
      }
      pf[ks] = w;
    }

    #pragma unroll
    for (int ks = 0; ks < 2; ++ks) {
      #pragma unroll
      for (int nt = 0; nt < 8; ++nt) {
        int d = nt * 16 + l15;
        int byteoff = ((d << 7) + (ks * 32 + 8 * hi) * 2) ^ ((((d >> 3) ^ d) & 7) << 4);
        short8 vvf = *reinterpret_cast<const short8*>(Vtlds + byteoff);
        o[nt] = __builtin_amdgcn_mfma_f32_16x16x32_bf16(pf[ks], vvf, o[nt], 0, 0, 0);
      }
    }
  }

  float rl = 1.0f / lsum;
  float rlO[4];
  #pragma unroll
  for (int i = 0; i < 4; ++i) rlO[i] = __shfl(rl, 4 * hi + i);
  const int qrow = q0 + wid * 16;
  #pragma unroll
  for (int nt = 0; nt < 8; ++nt)
    #pragma unroll
    for (int i = 0; i < 4; ++i)
      Ob[(size_t)(qrow + 4 * hi + i) * DD + nt * 16 + l15] = o[nt][i] * rlO[i];
}

extern "C" void kernel_launch(void* const* d_in, const int* in_sizes, int n_in,
                              void* d_out, int out_size, void* d_ws, size_t ws_size,
                              hipStream_t stream) {
  const float* Q = (const float*)d_in[0];
  const float* K = (const float*)d_in[1];
  const float* V = (const float*)d_in[2];
  float* O = (float*)d_out;

  if (ws_size >= WS_NEED) {
    char* ws = (char*)d_ws;
    prepack_kv<<<dim3(16, NTILES), 256, 0, stream>>>(K, V, ws);
    sdpa_causal_v2<<<dim3(16, 32), 256, 0, stream>>>(Q, ws, O);
  } else {
    sdpa_causal_kernel<<<dim3(16, 32), 256, 0, stream>>>(Q, K, V, O);
  }
}

// Round 3
// 59.829 us; speedup vs baseline: 1.2027x; 1.0833x over previous
//
#include <hip/hip_runtime.h>
#include <hip/hip_bf16.h>
#include <cstdint>

#define SS   2048
#define DD   128
#define QBLK 64
#define KBLK 64
#define NTILES (SS / KBLK)          // 32
#define TILE_BYTES 16384            // 64x128 bf16
#define CHUNK 16                    // K-tiles per chunk (1024 keys)

#define WS_KPRE   ((size_t)0)
#define WS_VPRE   ((size_t)16 * NTILES * TILE_BYTES)            // 16 MB
#define WS_PARTO  ((size_t)16 * NTILES * TILE_BYTES * 2)        // 32 MB
#define WS_PARTML (WS_PARTO + (size_t)16*16*2*64*128*4)         // +16 MB
#define WS_NEED_FULL (WS_PARTML + (size_t)16*16*2*64*2*4)       // +256 KB
#define WS_NEED_PRE  ((size_t)16 * NTILES * TILE_BYTES * 2)     // 32 MB

typedef __attribute__((ext_vector_type(8))) short short8;   // 8 bf16
typedef __attribute__((ext_vector_type(4))) float f32x4;    // MFMA C/D frag

__device__ __forceinline__ unsigned short f2bf(float x) {
  return __builtin_bit_cast(unsigned short, (__bf16)x);
}

// sigma: Vt column permutation so PV B-frag slots are contiguous 16B.
__device__ __forceinline__ int sigma_col(int a) {
  return (a & 35) | ((a & 12) << 1) | ((a & 16) >> 2);
}

// ---------------------------------------------------------------------------
// Pre-pass: K -> bf16 swizzled tiles; V -> transposed sigma-permuted swizzled
// ---------------------------------------------------------------------------
__global__ __launch_bounds__(256) void prepack_kv(
    const float* __restrict__ K, const float* __restrict__ V, char* __restrict__ ws)
{
  __shared__ float vf[64][129];
  const int b = blockIdx.x, t = blockIdx.y;
  const int tid = threadIdx.x;
  const float* Kt = K + ((size_t)b * SS + t * KBLK) * DD;
  const float* Vt = V + ((size_t)b * SS + t * KBLK) * DD;
  char* Kd = ws + WS_KPRE + ((size_t)(b * NTILES + t)) * TILE_BYTES;
  char* Vd = ws + WS_VPRE + ((size_t)(b * NTILES + t)) * TILE_BYTES;

  #pragma unroll
  for (int u = 0; u < 4; ++u) {
    int row = u * 16 + (tid >> 4);
    int col = 8 * (tid & 15);
    const float4* sp = reinterpret_cast<const float4*>(Kt + (size_t)row * DD + col);
    float4 x = sp[0], y = sp[1];
    short8 w;
    w[0] = f2bf(x.x); w[1] = f2bf(x.y); w[2] = f2bf(x.z); w[3] = f2bf(x.w);
    w[4] = f2bf(y.x); w[5] = f2bf(y.y); w[6] = f2bf(y.z); w[7] = f2bf(y.w);
    int off = (row * 256 + col * 2) ^ ((row & 7) << 4);
    *reinterpret_cast<short8*>(Kd + off) = w;
  }
  #pragma unroll
  for (int u = 0; u < 4; ++u) {
    int row = u * 16 + (tid >> 4);
    int col = 8 * (tid & 15);
    const float4* sp = reinterpret_cast<const float4*>(Vt + (size_t)row * DD + col);
    float4 x = sp[0], y = sp[1];
    vf[row][col + 0] = x.x; vf[row][col + 1] = x.y; vf[row][col + 2] = x.z; vf[row][col + 3] = x.w;
    vf[row][col + 4] = y.x; vf[row][col + 5] = y.y; vf[row][col + 6] = y.z; vf[row][col + 7] = y.w;
  }
  __syncthreads();
  #pragma unroll
  for (int q = 0; q < 4; ++q) {
    int idx = q * 256 + tid;
    int d = idx >> 3, y = idx & 7;
    short8 w;
    #pragma unroll
    for (int j = 0; j < 8; ++j) {
      int a = (j & 3) | ((y & 3) << 2) | ((j & 4) << 2) | ((y & 4) << 3);
      w[j] = f2bf(vf[a][d]);
    }
    int off = ((d << 7) + (y << 4)) ^ ((((d >> 3) ^ d) & 7) << 4);
    *reinterpret_cast<short8*>(Vd + off) = w;
  }
}

__device__ __forceinline__ void stage_tile(const char* Ksrc, const char* Vsrc,
                                           char* Kl, char* Vl, int wid, int lane)
{
  #pragma unroll
  for (int i = 0; i < 4; ++i) {
    int off = wid * 4096 + i * 1024;
    __builtin_amdgcn_global_load_lds(
        (const __attribute__((address_space(1))) unsigned int*)(Ksrc + off + lane * 16),
        (__attribute__((address_space(3))) unsigned int*)(Kl + off), 16, 0, 0);
  }
  #pragma unroll
  for (int i = 0; i < 4; ++i) {
    int off = wid * 4096 + i * 1024;
    __builtin_amdgcn_global_load_lds(
        (const __attribute__((address_space(1))) unsigned int*)(Vsrc + off + lane * 16),
        (__attribute__((address_space(3))) unsigned int*)(Vl + off), 16, 0, 0);
  }
}

// ---------------------------------------------------------------------------
// Main kernel: split-K chunks of <=16 tiles, uniform blocks, 768 total.
// slot s: [0,16)  -> qb=16+s, c=0, 16 tiles, no mask, partial
//         [16,32) -> qb=47-s, c=1, qb-15 tiles, mask, partial
//         [32,48) -> qb=47-s, c=0, qb+1 tiles, mask, direct store
// ---------------------------------------------------------------------------
__global__ __launch_bounds__(256) void sdpa_chunk(
    const float* __restrict__ Q, const char* __restrict__ ws,
    float* __restrict__ O, float* __restrict__ partO, float* __restrict__ partML)
{
  __shared__ __align__(16) char smem[2 * 32768];

  const int b = blockIdx.x;
  const int s = blockIdx.y;
  int qb, kvt0, ntile, pid = 0;
  bool domask, dostore;
  if (s < 16)      { qb = 16 + s; kvt0 = 0;  ntile = 16;      domask = false; dostore = false; pid = (qb-16)*2;   }
  else if (s < 32) { qb = 47 - s; kvt0 = 16; ntile = qb - 15; domask = true;  dostore = false; pid = (qb-16)*2+1; }
  else             { qb = 47 - s; kvt0 = 0;  ntile = qb + 1;  domask = true;  dostore = true; }

  const int q0 = qb * QBLK;
  const int tid = threadIdx.x;
  const int lane = tid & 63;
  const int wid  = tid >> 6;
  const int l15  = lane & 15;
  const int hi   = lane >> 4;

  const float* Qb = Q + (size_t)b * SS * DD;
  const char*  Kws = ws + WS_KPRE + ((size_t)b * NTILES + kvt0) * TILE_BYTES;
  const char*  Vws = ws + WS_VPRE + ((size_t)b * NTILES + kvt0) * TILE_BYTES;

  const float scale = 0.08838834764831845f;  // 1/sqrt(128)

  short8 qf[4];
  {
    const float* qrow = Qb + (size_t)(q0 + wid * 16 + l15) * DD;
    #pragma unroll
    for (int c = 0; c < 4; ++c) {
      const float4* p = reinterpret_cast<const float4*>(qrow + 32 * c + 8 * hi);
      float4 x = p[0], y2 = p[1];
      short8 w;
      w[0] = f2bf(x.x * scale); w[1] = f2bf(x.y * scale);
      w[2] = f2bf(x.z * scale); w[3] = f2bf(x.w * scale);
      w[4] = f2bf(y2.x * scale); w[5] = f2bf(y2.y * scale);
      w[6] = f2bf(y2.z * scale); w[7] = f2bf(y2.w * scale);
      qf[c] = w;
    }
  }

  f32x4 o[8];
  #pragma unroll
  for (int nt = 0; nt < 8; ++nt) o[nt] = (f32x4){0.f, 0.f, 0.f, 0.f};
  float m = -INFINITY;
  float lsum = 0.f;

  int cur = 0;
  stage_tile(Kws, Vws, smem, smem + 16384, wid, lane);
  __syncthreads();

  for (int t = 0; t < ntile; ++t) {
    if (t + 1 < ntile) {
      char* nb = smem + (cur ^ 1) * 32768;
      stage_tile(Kws + (size_t)(t + 1) * TILE_BYTES, Vws + (size_t)(t + 1) * TILE_BYTES,
                 nb, nb + 16384, wid, lane);
    }

    const char* Kl = smem + cur * 32768;
    const char* Vl = Kl + 16384;

    // ---- swapped QK^T ----
    f32x4 sacc[4];
    __builtin_amdgcn_s_setprio(1);
    #pragma unroll
    for (int g = 0; g < 4; ++g) {
      f32x4 acc = {0.f, 0.f, 0.f, 0.f};
      #pragma unroll
      for (int c = 0; c < 4; ++c) {
        int row = g * 16 + l15;
        int byteoff = (row * 256 + (32 * c + 8 * hi) * 2) ^ ((row & 7) << 4);
        short8 kf = *reinterpret_cast<const short8*>(Kl + byteoff);
        acc = __builtin_amdgcn_mfma_f32_16x16x32_bf16(kf, qf[c], acc, 0, 0, 0);
      }
      sacc[g] = acc;
    }
    __builtin_amdgcn_s_setprio(0);

    // ---- causal mask (diagonal tile only) ----
    if (domask && t == ntile - 1) {
      const int q = q0 + wid * 16 + l15;
      const int kv0 = (kvt0 + t) * KBLK;
      #pragma unroll
      for (int g = 0; g < 4; ++g)
        #pragma unroll
        for (int i = 0; i < 4; ++i) {
          int key = kv0 + g * 16 + 4 * hi + i;
          if (key > q) sacc[g][i] = -1e30f;
        }
    }

    // ---- online softmax, tree reductions ----
    float gm[4];
    #pragma unroll
    for (int g = 0; g < 4; ++g)
      gm[g] = fmaxf(fmaxf(sacc[g][0], sacc[g][1]), fmaxf(sacc[g][2], sacc[g][3]));
    float tmax = fmaxf(fmaxf(gm[0], gm[1]), fmaxf(gm[2], gm[3]));
    tmax = fmaxf(tmax, __shfl_xor(tmax, 16));
    tmax = fmaxf(tmax, __shfl_xor(tmax, 32));

    bool skip = __all(tmax <= m) && (t > 0 || m != -INFINITY);
    float mnew = skip ? m : fmaxf(m, tmax);
    float corr = skip ? 1.f : __expf(m - mnew);
    m = mnew;

    float p[4][4];
    float gs[4];
    #pragma unroll
    for (int g = 0; g < 4; ++g) {
      #pragma unroll
      for (int i = 0; i < 4; ++i) p[g][i] = __expf(sacc[g][i] - mnew);
      gs[g] = (p[g][0] + p[g][1]) + (p[g][2] + p[g][3]);
    }
    float psum = (gs[0] + gs[1]) + (gs[2] + gs[3]);
    psum += __shfl_xor(psum, 16);
    psum += __shfl_xor(psum, 32);
    lsum = lsum * corr + psum;

    if (!skip) {
      float corrO[4];
      #pragma unroll
      for (int i = 0; i < 4; ++i) corrO[i] = __shfl(corr, 4 * hi + i);
      #pragma unroll
      for (int nt = 0; nt < 8; ++nt)
        #pragma unroll
        for (int i = 0; i < 4; ++i) o[nt][i] *= corrO[i];
    }

    short8 pf[2];
    #pragma unroll
    for (int ks = 0; ks < 2; ++ks) {
      short8 w;
      #pragma unroll
      for (int i = 0; i < 4; ++i) {
        w[i]     = f2bf(p[2 * ks][i]);
        w[4 + i] = f2bf(p[2 * ks + 1][i]);
      }
      pf[ks] = w;
    }

    // ---- PV ----
    __builtin_amdgcn_s_setprio(1);
    #pragma unroll
    for (int ks = 0; ks < 2; ++ks) {
      #pragma unroll
      for (int nt = 0; nt < 8; ++nt) {
        int d = nt * 16 + l15;
        int byteoff = ((d << 7) + (ks * 32 + 8 * hi) * 2) ^ ((((d >> 3) ^ d) & 7) << 4);
        short8 vvf = *reinterpret_cast<const short8*>(Vl + byteoff);
        o[nt] = __builtin_amdgcn_mfma_f32_16x16x32_bf16(pf[ks], vvf, o[nt], 0, 0, 0);
      }
    }
    __builtin_amdgcn_s_setprio(0);

    if (t + 1 < ntile) {
      __syncthreads();
      cur ^= 1;
    }
  }

  // ---- epilogue ----
  if (dostore) {
    float rl = 1.0f / lsum;
    float rlO[4];
    #pragma unroll
    for (int i = 0; i < 4; ++i) rlO[i] = __shfl(rl, 4 * hi + i);
    float* Ob = O + (size_t)b * SS * DD;
    const int qrow = q0 + wid * 16;
    #pragma unroll
    for (int nt = 0; nt < 8; ++nt)
      #pragma unroll
      for (int i = 0; i < 4; ++i)
        Ob[(size_t)(qrow + 4 * hi + i) * DD + nt * 16 + l15] = o[nt][i] * rlO[i];
  } else {
    const int pbase = (b * 16 + (qb - 16)) * 2 + (s < 16 ? 0 : 1);
    float* po = partO + (size_t)pbase * (64 * 128);
    #pragma unroll
    for (int nt = 0; nt < 8; ++nt)
      #pragma unroll
      for (int i = 0; i < 4; ++i)
        po[(size_t)(wid * 16 + 4 * hi + i) * DD + nt * 16 + l15] = o[nt][i];
    if (hi == 0) {
      float2* ml = (float2*)partML;
      ml[pbase * 64 + wid * 16 + l15] = make_float2(m, lsum);
    }
  }
}

// ---------------------------------------------------------------------------
// Merge: combine the two partials of each qb>=16 row.
// ---------------------------------------------------------------------------
__global__ __launch_bounds__(256) void merge_partials(
    const float* __restrict__ partO, const float* __restrict__ partML,
    float* __restrict__ O)
{
  int idx = blockIdx.x * 256 + threadIdx.x;   // 524288 float4 slots
  int d4  = idx & 31;
  int row = (idx >> 5) & 63;
  int qr  = (idx >> 11) & 15;
  int b   = idx >> 15;
  int pid0 = (b * 16 + qr) * 2;
  float2 ml0 = ((const float2*)partML)[pid0 * 64 + row];
  float2 ml1 = ((const float2*)partML)[(pid0 + 1) * 64 + row];
  float M  = fmaxf(ml0.x, ml1.x);
  float a0 = __expf(ml0.x - M), a1 = __expf(ml1.x - M);
  float inv = 1.0f / (ml0.y * a0 + ml1.y * a1);
  float s0 = a0 * inv, s1 = a1 * inv;
  float4 o0 = ((const float4*)partO)[(size_t)pid0 * 2048 + row * 32 + d4];
  float4 o1 = ((const float4*)partO)[(size_t)(pid0 + 1) * 2048 + row * 32 + d4];
  float4 r;
  r.x = o0.x * s0 + o1.x * s1;
  r.y = o0.y * s0 + o1.y * s1;
  r.z = o0.z * s0 + o1.z * s1;
  r.w = o0.w * s0 + o1.w * s1;
  ((float4*)O)[((size_t)b * 2048 + (16 + qr) * 64 + row) * 32 + d4] = r;
}

// ---------------------------------------------------------------------------
// Fallback (round-2 kernel, co-residency-balanced pairing) if ws too small
// ---------------------------------------------------------------------------
__global__ __launch_bounds__(256) void sdpa_causal_v2(
    const float* __restrict__ Q, const char* __restrict__ ws, float* __restrict__ O)
{
  __shared__ __align__(16) char smem[2 * 32768];

  const int b = blockIdx.x;
  const int y = blockIdx.y;
  int qb0 = (y < 16) ? (31 - y) : (y - 16);
  const int qb = (b < 8) ? qb0 : (31 - qb0);   // pair (b, b+8) sums to 33 tiles
  const int q0 = qb * QBLK;
  const int tid = threadIdx.x;
  const int lane = tid & 63;
  const int wid  = tid >> 6;
  const int l15  = lane & 15;
  const int hi   = lane >> 4;

  const float* Qb = Q + (size_t)b * SS * DD;
  float*       Ob = O + (size_t)b * SS * DD;
  const char*  Kws = ws + WS_KPRE + ((size_t)b * NTILES) * TILE_BYTES;
  const char*  Vws = ws + WS_VPRE + ((size_t)b * NTILES) * TILE_BYTES;

  const float scale = 0.08838834764831845f;

  short8 qf[4];
  {
    const float* qrow = Qb + (size_t)(q0 + wid * 16 + l15) * DD;
    #pragma unroll
    for (int c = 0; c < 4; ++c) {
      const float4* p = reinterpret_cast<const float4*>(qrow + 32 * c + 8 * hi);
      float4 x = p[0], y2 = p[1];
      short8 w;
      w[0] = f2bf(x.x * scale); w[1] = f2bf(x.y * scale);
      w[2] = f2bf(x.z * scale); w[3] = f2bf(x.w * scale);
      w[4] = f2bf(y2.x * scale); w[5] = f2bf(y2.y * scale);
      w[6] = f2bf(y2.z * scale); w[7] = f2bf(y2.w * scale);
      qf[c] = w;
    }
  }

  f32x4 o[8];
  #pragma unroll
  for (int nt = 0; nt < 8; ++nt) o[nt] = (f32x4){0.f, 0.f, 0.f, 0.f};
  float m = -INFINITY;
  float lsum = 0.f;

  const int ntile = qb + 1;
  int cur = 0;
  stage_tile(Kws, Vws, smem, smem + 16384, wid, lane);
  __syncthreads();

  for (int t = 0; t < ntile; ++t) {
    if (t + 1 < ntile) {
      char* nb = smem + (cur ^ 1) * 32768;
      stage_tile(Kws + (size_t)(t + 1) * TILE_BYTES, Vws + (size_t)(t + 1) * TILE_BYTES,
                 nb, nb + 16384, wid, lane);
    }
    const char* Kl = smem + cur * 32768;
    const char* Vl = Kl + 16384;
    const int kv0 = t * KBLK;

    f32x4 sacc[4];
    #pragma unroll
    for (int g = 0; g < 4; ++g) {
      f32x4 acc = {0.f, 0.f, 0.f, 0.f};
      #pragma unroll
      for (int c = 0; c < 4; ++c) {
        int row = g * 16 + l15;
        int byteoff = (row * 256 + (32 * c + 8 * hi) * 2) ^ ((row & 7) << 4);
        short8 kf = *reinterpret_cast<const short8*>(Kl + byteoff);
        acc = __builtin_amdgcn_mfma_f32_16x16x32_bf16(kf, qf[c], acc, 0, 0, 0);
      }
      sacc[g] = acc;
    }

    if (t == ntile - 1) {
      const int q = q0 + wid * 16 + l15;
      #pragma unroll
      for (int g = 0; g < 4; ++g)
        #pragma unroll
        for (int i = 0; i < 4; ++i) {
          int key = kv0 + g * 16 + 4 * hi + i;
          if (key > q) sacc[g][i] = -1e30f;
        }
    }

    float tmax = -INFINITY;
    #pragma unroll
    for (int g = 0; g < 4; ++g)
      #pragma unroll
      for (int i = 0; i < 4; ++i) tmax = fmaxf(tmax, sacc[g][i]);
    tmax = fmaxf(tmax, __shfl_xor(tmax, 16));
    tmax = fmaxf(tmax, __shfl_xor(tmax, 32));
    float mnew = fmaxf(m, tmax);
    float corr = __expf(m - mnew);
    m = mnew;

    float p[4][4];
    float psum = 0.f;
    #pragma unroll
    for (int g = 0; g < 4; ++g)
      #pragma unroll
      for (int i = 0; i < 4; ++i) {
        float pv = __expf(sacc[g][i] - mnew);
        p[g][i] = pv;
        psum += pv;
      }
    psum += __shfl_xor(psum, 16);
    psum += __shfl_xor(psum, 32);
    lsum = lsum * corr + psum;

    float corrO[4];
    #pragma unroll
    for (int i = 0; i < 4; ++i) corrO[i] = __shfl(corr, 4 * hi + i);
    #pragma unroll
    for (int nt = 0; nt < 8; ++nt)
      #pragma unroll
      for (int i = 0; i < 4; ++i) o[nt][i] *= corrO[i];

    short8 pf[2];
    #pragma unroll
    for (int ks = 0; ks < 2; ++ks) {
      short8 w;
      #pragma unroll
      for (int i = 0; i < 4; ++i) {
        w[i]     = f2bf(p[2 * ks][i]);
        w[4 + i] = f2bf(p[2 * ks + 1][i]);
      }
      pf[ks] = w;
    }

    #pragma unroll
    for (int ks = 0; ks < 2; ++ks) {
      #pragma unroll
      for (int nt = 0; nt < 8; ++nt) {
        int d = nt * 16 + l15;
        int byteoff = ((d << 7) + (ks * 32 + 8 * hi) * 2) ^ ((((d >> 3) ^ d) & 7) << 4);
        short8 vvf = *reinterpret_cast<const short8*>(Vl + byteoff);
        o[nt] = __builtin_amdgcn_mfma_f32_16x16x32_bf16(pf[ks], vvf, o[nt], 0, 0, 0);
      }
    }

    if (t + 1 < ntile) {
      __syncthreads();
      cur ^= 1;
    }
  }

  float rl = 1.0f / lsum;
  float rlO[4];
  #pragma unroll
  for (int i = 0; i < 4; ++i) rlO[i] = __shfl(rl, 4 * hi + i);
  const int qrow = q0 + wid * 16;
  #pragma unroll
  for (int nt = 0; nt < 8; ++nt)
    #pragma unroll
    for (int i = 0; i < 4; ++i)
      Ob[(size_t)(qrow + 4 * hi + i) * DD + nt * 16 + l15] = o[nt][i] * rlO[i];
}

extern "C" void kernel_launch(void* const* d_in, const int* in_sizes, int n_in,
                              void* d_out, int out_size, void* d_ws, size_t ws_size,
                              hipStream_t stream) {
  const float* Q = (const float*)d_in[0];
  const float* K = (const float*)d_in[1];
  const float* V = (const float*)d_in[2];
  float* O = (float*)d_out;
  char* ws = (char*)d_ws;

  if (ws_size >= WS_NEED_FULL) {
    float* partO  = (float*)(ws + WS_PARTO);
    float* partML = (float*)(ws + WS_PARTML);
    prepack_kv<<<dim3(16, NTILES), 256, 0, stream>>>(K, V, ws);
    sdpa_chunk<<<dim3(16, 48), 256, 0, stream>>>(Q, ws, O, partO, partML);
    merge_partials<<<2048, 256, 0, stream>>>(partO, partML, O);
  } else if (ws_size >= WS_NEED_PRE) {
    prepack_kv<<<dim3(16, NTILES), 256, 0, stream>>>(K, V, ws);
    sdpa_causal_v2<<<dim3(16, 32), 256, 0, stream>>>(Q, ws, O);
  }
}